// Round 5
// baseline (174.624 us; speedup 1.0000x reference)
//
#include <hip/hip_runtime.h>
#include <hip/hip_bf16.h>

#define L_SEQ 2048
#define DM 512

typedef short bf16x8 __attribute__((ext_vector_type(8)));
typedef float f32x4 __attribute__((ext_vector_type(4)));
typedef unsigned short u16;
typedef u16 u16x8 __attribute__((ext_vector_type(8)));
typedef u16 u16x4 __attribute__((ext_vector_type(4)));

__device__ __forceinline__ u16 f2bf(float f) {
    unsigned int u = __float_as_uint(f);
    u += 0x7fffu + ((u >> 16) & 1u);
    return (u16)(u >> 16);
}

__device__ __forceinline__ unsigned int pk_bf16(float a, float b) {
    __hip_bfloat162 h = __float22bfloat162_rn(float2{a, b});
    unsigned int u;
    __builtin_memcpy(&u, &h, 4);
    return u;
}

__device__ __forceinline__ void lds_load16(const void* g, void* l) {
    __builtin_amdgcn_global_load_lds(
        (const __attribute__((address_space(1))) unsigned int*)g,
        (__attribute__((address_space(3))) unsigned int*)l,
        16, 0, 0);
}

// ---------------- fp32 -> bf16 (3 weight matrices) ----------------
__global__ void cvt_w(const float* __restrict__ Wq, const float* __restrict__ Wk,
                      const float* __restrict__ Wv, u16* __restrict__ dst) {
    int i = blockIdx.x * blockDim.x + threadIdx.x;
    int which = i >> 16, j = i & 65535;
    const float* src = (which == 0) ? Wq : (which == 1 ? Wk : Wv);
    float4 v = ((const float4*)src)[j];
    ushort4 o;
    o.x = f2bf(v.x); o.y = f2bf(v.y); o.z = f2bf(v.z); o.w = f2bf(v.w);
    ((ushort4*)dst)[i] = o;
}

// ---------------- x [B][512][2048] fp32 -> xT [B][2048][512] bf16, 128x128 tiles ----------------
__global__ void tr_cvt_x(const float* __restrict__ x1, const float* __restrict__ x2,
                         u16* __restrict__ dst) {
    __shared__ u16 t[128 * 136];   // [c][l] bf16, pitch 136
    const int z = blockIdx.z, b = z & 3, c0 = blockIdx.y * 128, l0 = blockIdx.x * 128;
    const float* src = (z < 4) ? x1 : x2;
    u16* dbase = dst + (size_t)(z >> 2) * 4194304;
    const int tid = threadIdx.x;
    const float* sp = src + ((size_t)b * DM + c0) * L_SEQ + l0;
#pragma unroll
    for (int p = 0; p < 16; ++p) {
        int id = p * 256 + tid;
        int ci = id >> 5, f4 = id & 31;
        float4 v = *(const float4*)(sp + (size_t)ci * L_SEQ + f4 * 4);
        u16x4 o;
        o[0] = f2bf(v.x); o[1] = f2bf(v.y); o[2] = f2bf(v.z); o[3] = f2bf(v.w);
        *(u16x4*)(t + ci * 136 + f4 * 4) = o;
    }
    __syncthreads();
    u16* dp = dbase + ((size_t)b * L_SEQ + l0) * DM + c0;
#pragma unroll
    for (int p = 0; p < 8; ++p) {
        int id = p * 256 + tid;
        int lj = id >> 4, c8 = id & 15;
        u16x8 o;
#pragma unroll
        for (int i = 0; i < 8; ++i) o[i] = t[(c8 * 8 + i) * 136 + lj];
        *(u16x8*)(dp + (size_t)lj * DM + c8 * 8) = o;
    }
}

// ---------------- fused QKV projection GEMM (ping-pong staged) ----------------
// Y[l][dout] = sum_c xT[l][c] * W[dout][c] + bias.  128x128 tile, BK=32, 16 iters.
__launch_bounds__(256, 3)
__global__ void proj_gemm(const u16* __restrict__ x1T, const u16* __restrict__ x2T,
                          const u16* __restrict__ Wall,
                          const float* __restrict__ bq, const float* __restrict__ bk,
                          const float* __restrict__ bv,
                          u16* __restrict__ Qo, u16* __restrict__ Ko, u16* __restrict__ Vto) {
    __shared__ __align__(16) char smem[34816];
    // abuf0 @0, bbuf0 @8K, abuf1 @16K, bbuf1 @24K (8 KB each); epi overlays all
    const int by = blockIdx.y;
    const int b = by / 3, pj = by % 3;
    const int m0 = (blockIdx.x >> 2) * 128, n0 = (blockIdx.x & 3) * 128;
    const u16* xT = (pj == 0) ? x1T : x2T;
    const u16* W = Wall + (size_t)pj * 262144;
    const float* bias = (pj == 0) ? bq : (pj == 1 ? bk : bv);
    const float scale = (pj == 0) ? 0.18033688011112042f : 1.0f; // (1/8)*log2(e)

    const int tid = threadIdx.x;
    const int w = tid >> 6, lane = tid & 63;
    const int lm = lane & 15, lq = lane >> 4;
    const int wrow = (w & 1) * 64, wcol = (w >> 1) * 64;

    // staging: A slots s=j*256+tid (j=0,1), B slots likewise; r=s>>2, c=s&3, cc=c^(r&3)
    const u16* gA[2]; const u16* gB[2];
    int adst[2];
#pragma unroll
    for (int j = 0; j < 2; ++j) {
        int s = j * 256 + tid;
        int r = s >> 2, c = s & 3, cc = c ^ (r & 3);
        gA[j] = xT + ((size_t)b * L_SEQ + m0 + r) * DM + cc * 8;
        gB[j] = W + (size_t)(n0 + r) * DM + cc * 8;
        adst[j] = (j * 256 + w * 64) * 8;   // u16 units, wave-uniform base
    }

    f32x4 acc[4][4];
#pragma unroll
    for (int mt = 0; mt < 4; ++mt)
#pragma unroll
        for (int nt = 0; nt < 4; ++nt) acc[mt][nt] = (f32x4){0.f, 0.f, 0.f, 0.f};

    // prologue: stage tile 0 into buf0
#pragma unroll
    for (int j = 0; j < 2; ++j) {
        lds_load16(gA[j], (u16*)smem + adst[j]);
        lds_load16(gB[j], (u16*)(smem + 8192) + adst[j]);
    }

    for (int kt = 0; kt < 16; ++kt) {
        __syncthreads();   // drains this wave's outstanding staging (issued last iter)
        if (kt < 15) {
            int nb = (kt + 1) & 1;
#pragma unroll
            for (int j = 0; j < 2; ++j) {
                lds_load16(gA[j] + (kt + 1) * 32, (u16*)(smem + nb * 16384) + adst[j]);
                lds_load16(gB[j] + (kt + 1) * 32, (u16*)(smem + 8192 + nb * 16384) + adst[j]);
            }
        }
        const u16* a_lds = (const u16*)(smem + (kt & 1) * 16384);
        const u16* b_lds = (const u16*)(smem + 8192 + (kt & 1) * 16384);
        bf16x8 af[4], bfr[4];
#pragma unroll
        for (int mt = 0; mt < 4; ++mt) {
            int r = wrow + mt * 16 + lm;
            af[mt] = *(const bf16x8*)(a_lds + r * 32 + (lq ^ (r & 3)) * 8);
        }
#pragma unroll
        for (int nt = 0; nt < 4; ++nt) {
            int r = wcol + nt * 16 + lm;
            bfr[nt] = *(const bf16x8*)(b_lds + r * 32 + (lq ^ (r & 3)) * 8);
        }
#pragma unroll
        for (int mt = 0; mt < 4; ++mt)
#pragma unroll
            for (int nt = 0; nt < 4; ++nt)
                acc[mt][nt] = __builtin_amdgcn_mfma_f32_16x16x32_bf16(af[mt], bfr[nt], acc[mt][nt], 0, 0, 0);
    }

    float bvv[4];
#pragma unroll
    for (int nt = 0; nt < 4; ++nt) bvv[nt] = bias[n0 + wcol + nt * 16 + lm];

    // unified epilogue: stage epi[dout][l] (pitch 136) then coalesced global writes
    __syncthreads();
    u16* epi = (u16*)smem;
#pragma unroll
    for (int mt = 0; mt < 4; ++mt)
#pragma unroll
        for (int nt = 0; nt < 4; ++nt) {
            int colL = wcol + nt * 16 + lm;      // dout within tile
            int row0 = wrow + mt * 16 + lq * 4;  // l within tile
            u16x4 tv;
#pragma unroll
            for (int r = 0; r < 4; ++r) tv[r] = f2bf((acc[mt][nt][r] + bvv[nt]) * scale);
            *(u16x4*)(epi + colL * 136 + row0) = tv;
        }
    __syncthreads();
    if (pj < 2) {
        u16* dst = (pj == 0) ? Qo : Ko;
#pragma unroll
        for (int p = 0; p < 8; ++p) {
            int id = p * 256 + tid;
            int lj = id >> 4, c8 = id & 15;
            u16x8 o;
#pragma unroll
            for (int i = 0; i < 8; ++i) o[i] = epi[(c8 * 8 + i) * 136 + lj];
            *(u16x8*)(dst + ((size_t)b * L_SEQ + m0 + lj) * DM + n0 + c8 * 8) = o;
        }
    } else {
#pragma unroll
        for (int p = 0; p < 8; ++p) {
            int id = p * 256 + tid;
            int rr = id >> 4, ch = id & 15;
            u16x8 vv = *(const u16x8*)(epi + rr * 136 + ch * 8);
            *(u16x8*)(Vto + ((size_t)b * DM + n0 + rr) * L_SEQ + m0 + ch * 8) = vv;
        }
    }
}

// ---------------- flash attention: BN=64 ping-pong, XCD-swizzled ----------------
// 512 blocks x 512 threads. BM=128 q rows (16/wave), 32 key-tiles of 64.
__launch_bounds__(512, 4)
__global__ void attn(const u16* __restrict__ Q, const u16* __restrict__ K,
                     const u16* __restrict__ Vt, float* __restrict__ out) {
    __shared__ __align__(16) char smem[49664];
    // kbuf0 @0, kbuf1 @8K, vbuf0 @16K, vbuf1 @24K, p @32K (16K), l @48K (512B)
    u16* p_lds = (u16*)(smem + 32768);      // [128 q][8 chunks of 8 keys], ch^(q&7)
    float* l_lds = (float*)(smem + 49152);  // [128] reciprocal row sums
    float* o_lds = (float*)smem;            // epilogue overlay: [64 d][128], 32 KB

    // XCD swizzle: all 16 q-blocks of one (b,h) share (blockIdx.x & 7) -> same XCD L2
    const int i = blockIdx.x;
    const int g = i & 7, r_ = i >> 3;
    const int qb = r_ & 15, bh = ((r_ >> 4) << 3) + g;
    const int h = bh >> 2, b = bh & 3;

    const int tid = threadIdx.x, w = tid >> 6, lane = tid & 63;
    const int q0 = qb * 128, wr = w * 16;
    const int lm = lane & 15, lq = lane >> 4;

    const u16* Qb = Q + ((size_t)b * L_SEQ + q0) * DM + h * 64;
    const u16* Kb = K + (size_t)b * L_SEQ * DM + h * 64;
    const u16* Vb = Vt + ((size_t)b * DM + h * 64) * L_SEQ;

    // K/V tile staging: 512 slots, 1 load/thread each. s=tid: K row r=s>>3 (64), chunk c=s&7
    const u16 *gK, *gV;
    int sdst;
    {
        int r = tid >> 3, c = tid & 7, cc = c ^ (r & 7);
        gK = Kb + (size_t)r * DM + cc * 8;
        gV = Vb + (size_t)r * L_SEQ + cc * 8;   // r = d row for V
        sdst = (w * 64) * 8;                    // wave-uniform base (u16 units)
    }

    // ---- stage Q (128x64) into kbuf0+kbuf1, read B-layout fragments ----
#pragma unroll
    for (int j = 0; j < 2; ++j) {
        int s = j * 512 + tid;
        int r = s >> 3, c = s & 7, cc = c ^ (r & 7);
        lds_load16(Qb + (size_t)r * DM + cc * 8, (u16*)(smem + j * 8192) + sdst);
    }
    __syncthreads();
    bf16x8 qf[2];
#pragma unroll
    for (int kb = 0; kb < 2; ++kb) {
        int r = wr + lm;
        const u16* qsrc = (const u16*)(smem + (r >> 6) * 8192)
                          + (r & 63) * 64 + ((kb * 4 + lq) ^ (r & 7)) * 8;
        qf[kb] = *(const bf16x8*)qsrc;
    }
    __syncthreads();   // all waves done reading Q; kbufs reusable

    float l_part = 0.f;
    f32x4 o_acc[4];
#pragma unroll
    for (int dt = 0; dt < 4; ++dt) o_acc[dt] = (f32x4){0.f, 0.f, 0.f, 0.f};

    // prologue: stage tile 0
    lds_load16(gK, (u16*)smem + sdst);
    lds_load16(gV, (u16*)(smem + 16384) + sdst);

    for (int kt = 0; kt < 32; ++kt) {
        __syncthreads();   // drains this wave's tile-kt loads (in flight during prev compute)
        if (kt < 31) {
            int nb = (kt + 1) & 1;
            lds_load16(gK + (size_t)(kt + 1) * 64 * DM, (u16*)(smem + nb * 8192) + sdst);
            lds_load16(gV + (kt + 1) * 64, (u16*)(smem + 16384 + nb * 8192) + sdst);
        }
        const u16* kl = (const u16*)(smem + (kt & 1) * 8192);
        const u16* vl = (const u16*)(smem + 16384 + (kt & 1) * 8192);

        // S^T = K Q^T: lane holds 4 consecutive keys at fixed q=lm
#pragma unroll
        for (int nt = 0; nt < 4; ++nt) {
            int rk = nt * 16 + lm;
            bf16x8 kf0 = *(const bf16x8*)(kl + rk * 64 + ((0 + lq) ^ (rk & 7)) * 8);
            bf16x8 kf1 = *(const bf16x8*)(kl + rk * 64 + ((4 + lq) ^ (rk & 7)) * 8);
            f32x4 s = (f32x4){0.f, 0.f, 0.f, 0.f};
            s = __builtin_amdgcn_mfma_f32_16x16x32_bf16(kf0, qf[0], s, 0, 0, 0);
            s = __builtin_amdgcn_mfma_f32_16x16x32_bf16(kf1, qf[1], s, 0, 0, 0);
            float p0 = __builtin_amdgcn_exp2f(s[0]);
            float p1 = __builtin_amdgcn_exp2f(s[1]);
            float p2 = __builtin_amdgcn_exp2f(s[2]);
            float p3 = __builtin_amdgcn_exp2f(s[3]);
            l_part += (p0 + p1) + (p2 + p3);
            unsigned int w0 = pk_bf16(p0, p1), w1 = pk_bf16(p2, p3);
            int q = wr + lm;
            int c8 = nt * 2 + (lq >> 1);
            int chs = c8 ^ (q & 7);
            uint2 pw; pw.x = w0; pw.y = w1;
            *(uint2*)(p_lds + q * 64 + chs * 8 + (lq & 1) * 4) = pw;
        }
        // wave-local P RAW (no barrier; each wave reads only its own 16 rows)

        // O += P V
#pragma unroll
        for (int kb = 0; kb < 2; ++kb) {
            int r = wr + lm;
            bf16x8 pf = *(const bf16x8*)(p_lds + r * 64 + ((kb * 4 + lq) ^ (r & 7)) * 8);
#pragma unroll
            for (int dt = 0; dt < 4; ++dt) {
                int d = dt * 16 + lm;
                bf16x8 vf = *(const bf16x8*)(vl + d * 64 + ((kb * 4 + lq) ^ (d & 7)) * 8);
                o_acc[dt] = __builtin_amdgcn_mfma_f32_16x16x32_bf16(pf, vf, o_acc[dt], 0, 0, 0);
            }
        }
    }

    // reduce l across the 4 lq lanes sharing each q=lm
    l_part += __shfl_xor(l_part, 16);
    l_part += __shfl_xor(l_part, 32);

    __syncthreads();   // all waves done with k/v bufs; reuse as o_lds
    if (lq == 0) l_lds[wr + lm] = 1.0f / l_part;
    {
        int rc = w * 4 + lq;   // (wr + lq*4) >> 2
#pragma unroll
        for (int dt = 0; dt < 4; ++dt) {
            int col = dt * 16 + lm;
            *(f32x4*)(o_lds + col * 128 + ((rc ^ (col & 31)) << 2)) = o_acc[dt];
        }
    }
    __syncthreads();
    float* ob = out + ((size_t)b * DM + h * 64) * L_SEQ + q0;
#pragma unroll
    for (int p = 0; p < 4; ++p) {
        int id = p * 512 + tid;
        int d = id >> 5, rc = id & 31;
        f32x4 vv = *(const f32x4*)(o_lds + d * 128 + ((rc ^ (d & 31)) << 2));
        f32x4 il = *(const f32x4*)(l_lds + rc * 4);
#pragma unroll
        for (int j = 0; j < 4; ++j) vv[j] *= il[j];
        *(f32x4*)(ob + (size_t)d * L_SEQ + rc * 4) = vv;
    }
}

extern "C" void kernel_launch(void* const* d_in, const int* in_sizes, int n_in,
                              void* d_out, int out_size, void* d_ws, size_t ws_size,
                              hipStream_t stream) {
    const float* x1 = (const float*)d_in[0];
    const float* x2 = (const float*)d_in[1];
    const float* Wq = (const float*)d_in[2];
    const float* bq = (const float*)d_in[3];
    const float* Wk = (const float*)d_in[4];
    const float* bk = (const float*)d_in[5];
    const float* Wv = (const float*)d_in[6];
    const float* bv = (const float*)d_in[7];
    float* out = (float*)d_out;

    char* ws = (char*)d_ws;
    u16* x1T = (u16*)(ws);
    u16* x2T = (u16*)(ws + 8388608);
    u16* Wall = (u16*)(ws + 16777216);
    u16* Qb  = (u16*)(ws + 18350080);
    u16* Kb  = (u16*)(ws + 26738688);
    u16* Vtb = (u16*)(ws + 35127296);

    cvt_w<<<768, 256, 0, stream>>>(Wq, Wk, Wv, Wall);
    tr_cvt_x<<<dim3(16, 4, 8), 256, 0, stream>>>(x1, x2, x1T);
    proj_gemm<<<dim3(64, 12), 256, 0, stream>>>(x1T, x2T, Wall, bq, bk, bv, Qb, Kb, Vtb);
    attn<<<512, 512, 0, stream>>>(Qb, Kb, Vtb, out);
}

// Round 6
// 166.596 us; speedup vs baseline: 1.0482x; 1.0482x over previous
//
#include <hip/hip_runtime.h>
#include <hip/hip_bf16.h>

#define L_SEQ 2048
#define DM 512

typedef short bf16x8 __attribute__((ext_vector_type(8)));
typedef float f32x4 __attribute__((ext_vector_type(4)));
typedef float f32x16 __attribute__((ext_vector_type(16)));
typedef unsigned short u16;
typedef u16 u16x8 __attribute__((ext_vector_type(8)));
typedef u16 u16x4 __attribute__((ext_vector_type(4)));

__device__ __forceinline__ u16 f2bf(float f) {
    unsigned int u = __float_as_uint(f);
    u += 0x7fffu + ((u >> 16) & 1u);
    return (u16)(u >> 16);
}

__device__ __forceinline__ unsigned int pk_bf16(float a, float b) {
    __hip_bfloat162 h = __float22bfloat162_rn(float2{a, b});
    unsigned int u;
    __builtin_memcpy(&u, &h, 4);
    return u;
}

__device__ __forceinline__ void lds_load16(const void* g, void* l) {
    __builtin_amdgcn_global_load_lds(
        (const __attribute__((address_space(1))) unsigned int*)g,
        (__attribute__((address_space(3))) unsigned int*)l,
        16, 0, 0);
}

__device__ __forceinline__ f32x16 zero16() {
    f32x16 z;
#pragma unroll
    for (int i = 0; i < 16; ++i) z[i] = 0.f;
    return z;
}

// ---------------- fp32 -> bf16 (3 weight matrices) ----------------
__global__ void cvt_w(const float* __restrict__ Wq, const float* __restrict__ Wk,
                      const float* __restrict__ Wv, u16* __restrict__ dst) {
    int i = blockIdx.x * blockDim.x + threadIdx.x;
    int which = i >> 16, j = i & 65535;
    const float* src = (which == 0) ? Wq : (which == 1 ? Wk : Wv);
    float4 v = ((const float4*)src)[j];
    ushort4 o;
    o.x = f2bf(v.x); o.y = f2bf(v.y); o.z = f2bf(v.z); o.w = f2bf(v.w);
    ((ushort4*)dst)[i] = o;
}

// ---------------- x [B][512][2048] fp32 -> xT [B][2048][512] bf16, 128x128 tiles ----------------
__global__ void tr_cvt_x(const float* __restrict__ x1, const float* __restrict__ x2,
                         u16* __restrict__ dst) {
    __shared__ u16 t[128 * 136];
    const int z = blockIdx.z, b = z & 3, c0 = blockIdx.y * 128, l0 = blockIdx.x * 128;
    const float* src = (z < 4) ? x1 : x2;
    u16* dbase = dst + (size_t)(z >> 2) * 4194304;
    const int tid = threadIdx.x;
    const float* sp = src + ((size_t)b * DM + c0) * L_SEQ + l0;
#pragma unroll
    for (int p = 0; p < 16; ++p) {
        int id = p * 256 + tid;
        int ci = id >> 5, f4 = id & 31;
        float4 v = *(const float4*)(sp + (size_t)ci * L_SEQ + f4 * 4);
        u16x4 o;
        o[0] = f2bf(v.x); o[1] = f2bf(v.y); o[2] = f2bf(v.z); o[3] = f2bf(v.w);
        *(u16x4*)(t + ci * 136 + f4 * 4) = o;
    }
    __syncthreads();
    u16* dp = dbase + ((size_t)b * L_SEQ + l0) * DM + c0;
#pragma unroll
    for (int p = 0; p < 8; ++p) {
        int id = p * 256 + tid;
        int lj = id >> 4, c8 = id & 15;
        u16x8 o;
#pragma unroll
        for (int i = 0; i < 8; ++i) o[i] = t[(c8 * 8 + i) * 136 + lj];
        *(u16x8*)(dp + (size_t)lj * DM + c8 * 8) = o;
    }
}

// ---------------- fused QKV projection GEMM (R3 structure, known-good) ----------------
__launch_bounds__(256, 2)
__global__ void proj_gemm(const u16* __restrict__ x1T, const u16* __restrict__ x2T,
                          const u16* __restrict__ Wall,
                          const float* __restrict__ bq, const float* __restrict__ bk,
                          const float* __restrict__ bv,
                          u16* __restrict__ Qo, u16* __restrict__ Ko, u16* __restrict__ Vto) {
    __shared__ __align__(16) char smem[34816];
    u16* a_lds = (u16*)smem;
    u16* b_lds = (u16*)(smem + 8192);
    const int by = blockIdx.y;
    const int b = by / 3, pj = by % 3;
    const int m0 = (blockIdx.x >> 2) * 128, n0 = (blockIdx.x & 3) * 128;
    const u16* xT = (pj == 0) ? x1T : x2T;
    const u16* W = Wall + (size_t)pj * 262144;
    const float* bias = (pj == 0) ? bq : (pj == 1 ? bk : bv);
    const float scale = (pj == 0) ? 0.18033688011112042f : 1.0f;

    const int tid = threadIdx.x;
    const int w = tid >> 6, lane = tid & 63;
    const int lm = lane & 15, lq = lane >> 4;
    const int wrow = (w & 1) * 64, wcol = (w >> 1) * 64;

    const u16* gsrc[4];
    int loff[4];
#pragma unroll
    for (int j = 0; j < 4; ++j) {
        int s = (j & 1) * 256 + w * 64 + lane;
        int r = s >> 2, c = s & 3, cc = c ^ (r & 3);
        if (j < 2) gsrc[j] = xT + ((size_t)b * L_SEQ + m0 + r) * DM + cc * 8;
        else       gsrc[j] = W + (size_t)(n0 + r) * DM + cc * 8;
        loff[j] = ((j & 1) * 256 + w * 64) * 8;
    }

    f32x4 acc[4][4];
#pragma unroll
    for (int mt = 0; mt < 4; ++mt)
#pragma unroll
        for (int nt = 0; nt < 4; ++nt) acc[mt][nt] = (f32x4){0.f, 0.f, 0.f, 0.f};

    for (int kt = 0; kt < 16; ++kt) {
        __syncthreads();
#pragma unroll
        for (int j = 0; j < 4; ++j)
            lds_load16(gsrc[j] + kt * 32, (j < 2 ? a_lds : b_lds) + loff[j]);
        __syncthreads();
        bf16x8 af[4], bfr[4];
#pragma unroll
        for (int mt = 0; mt < 4; ++mt) {
            int r = wrow + mt * 16 + lm;
            af[mt] = *(const bf16x8*)(a_lds + r * 32 + (lq ^ (r & 3)) * 8);
        }
#pragma unroll
        for (int nt = 0; nt < 4; ++nt) {
            int r = wcol + nt * 16 + lm;
            bfr[nt] = *(const bf16x8*)(b_lds + r * 32 + (lq ^ (r & 3)) * 8);
        }
#pragma unroll
        for (int mt = 0; mt < 4; ++mt)
#pragma unroll
            for (int nt = 0; nt < 4; ++nt)
                acc[mt][nt] = __builtin_amdgcn_mfma_f32_16x16x32_bf16(af[mt], bfr[nt], acc[mt][nt], 0, 0, 0);
    }

    float bvv[4];
#pragma unroll
    for (int nt = 0; nt < 4; ++nt) bvv[nt] = bias[n0 + wcol + nt * 16 + lm];

    if (pj < 2) {
        u16* dst = (pj == 0) ? Qo : Ko;
#pragma unroll
        for (int mt = 0; mt < 4; ++mt)
#pragma unroll
            for (int nt = 0; nt < 4; ++nt) {
                int col = n0 + wcol + nt * 16 + lm;
#pragma unroll
                for (int r = 0; r < 4; ++r) {
                    int row = m0 + wrow + mt * 16 + lq * 4 + r;
                    dst[((size_t)b * L_SEQ + row) * DM + col] = f2bf((acc[mt][nt][r] + bvv[nt]) * scale);
                }
            }
    } else {
        __syncthreads();
        u16* epi = (u16*)smem;
#pragma unroll
        for (int mt = 0; mt < 4; ++mt)
#pragma unroll
            for (int nt = 0; nt < 4; ++nt) {
                int colL = wcol + nt * 16 + lm;
                int row0 = wrow + mt * 16 + lq * 4;
                u16x4 tv;
#pragma unroll
                for (int r = 0; r < 4; ++r) tv[r] = f2bf(acc[mt][nt][r] + bvv[nt]);
                *(u16x4*)(epi + colL * 136 + row0) = tv;
            }
        __syncthreads();
#pragma unroll
        for (int p = 0; p < 8; ++p) {
            int id = p * 256 + tid;
            int rr = id >> 4, ch = id & 15;
            u16x8 vv = *(const u16x8*)(epi + rr * 136 + ch * 8);
            *(u16x8*)(Vto + ((size_t)b * DM + n0 + rr) * L_SEQ + m0 + ch * 8) = vv;
        }
    }
}

// ---------------- flash attention: 32x32x16 MFMA, 4 waves x 32q, BN=64 ping-pong ----------------
// 512 blocks x 256 threads, 3 blocks/CU. Halved K/V LDS re-read redundancy vs 16x16 version.
__launch_bounds__(256, 3)
__global__ void attn(const u16* __restrict__ Q, const u16* __restrict__ K,
                     const u16* __restrict__ Vt, float* __restrict__ out) {
    __shared__ __align__(16) char smem[50688];
    // kbuf0 @0, kbuf1 @8K, vbuf0 @16K, vbuf1 @24K (8KB each)
    // p_lds @32768: [128 q][pitch 68 u16] = 17408 B
    // l_lds @50176: 128 f32
    // o_lds overlay @0: [64 d][pitch 132 f32] = 33792 B (kv+p head dead by then)
    u16* p_lds = (u16*)(smem + 32768);
    float* l_lds = (float*)(smem + 50176);
    float* o_lds = (float*)smem;

    const int i = blockIdx.x;
    const int g = i & 7, r_ = i >> 3;
    const int qb = r_ & 15, bh = ((r_ >> 4) << 3) + g;
    const int h_ = bh >> 2, b = bh & 3;

    const int tid = threadIdx.x, w = tid >> 6, lane = tid & 63;
    const int q0 = qb * 128, wr = w * 32;
    const int lm32 = lane & 31, hi = lane >> 5;
    const int qrow = wr + lm32;     // this lane's q row (S-phase col / PV-phase A row)

    const u16* Qb = Q + ((size_t)b * L_SEQ + q0) * DM + h_ * 64;
    const u16* Kb = K + (size_t)b * L_SEQ * DM + h_ * 64;
    const u16* Vb = Vt + ((size_t)b * DM + h_ * 64) * L_SEQ;

    // K/V staging: 8KB tile = 512 slots of 16B; 256 threads -> 2 loads each
    const u16 *gK[2], *gV[2];
    int soff[2];
#pragma unroll
    for (int j = 0; j < 2; ++j) {
        int s = j * 256 + tid;
        int r = s >> 3, c = s & 7, cc = c ^ (r & 7);
        gK[j] = Kb + (size_t)r * DM + cc * 8;
        gV[j] = Vb + (size_t)r * L_SEQ + cc * 8;   // r = d row for V
        soff[j] = (j * 256 + w * 64) * 8;          // u16 units, wave-uniform base
    }

    // ---- stage Q (128x64 = 16KB) into kbuf0+kbuf1 ----
#pragma unroll
    for (int j = 0; j < 4; ++j) {
        int s = j * 256 + tid;
        int r = s >> 3, c = s & 7, cc = c ^ (r & 7);
        lds_load16(Qb + (size_t)r * DM + cc * 8, (u16*)smem + (j * 256 + w * 64) * 8);
    }
    __syncthreads();
    // Q B-frags: B[k=d][n=q]: n = lane&31 -> qrow; d = 16c + 8*hi + j
    bf16x8 qf[4];
#pragma unroll
    for (int c = 0; c < 4; ++c) {
        int slot = (2 * c + hi) ^ (qrow & 7);
        qf[c] = *(const bf16x8*)((const u16*)smem + qrow * 64 + slot * 8);
    }
    __syncthreads();   // Q read done; kbufs reusable

    float l_part = 0.f;
    f32x16 o_acc[2];
    o_acc[0] = zero16(); o_acc[1] = zero16();

    // prologue: stage K/V tile 0
#pragma unroll
    for (int j = 0; j < 2; ++j) {
        lds_load16(gK[j], (u16*)smem + soff[j]);
        lds_load16(gV[j], (u16*)(smem + 16384) + soff[j]);
    }

    u16* prow = p_lds + qrow * 68;

    for (int kt = 0; kt < 32; ++kt) {
        __syncthreads();   // drains tile-kt loads (issued last iter, landed during compute)
        if (kt < 31) {
            int nb = (kt + 1) & 1;
#pragma unroll
            for (int j = 0; j < 2; ++j) {
                lds_load16(gK[j] + (size_t)(kt + 1) * 64 * DM, (u16*)(smem + nb * 8192) + soff[j]);
                lds_load16(gV[j] + (kt + 1) * 64, (u16*)(smem + 16384 + nb * 8192) + soff[j]);
            }
        }
        const u16* kl = (const u16*)(smem + (kt & 1) * 8192);
        const u16* vl = (const u16*)(smem + 16384 + (kt & 1) * 8192);

        // S^T = K Q^T per 32-key block: A = K (m=key), B = Q (n=q)
#pragma unroll
        for (int kb2 = 0; kb2 < 2; ++kb2) {
            int rk = kb2 * 32 + lm32;
            f32x16 s = zero16();
#pragma unroll
            for (int c = 0; c < 4; ++c) {
                int slot = (2 * c + hi) ^ (rk & 7);
                bf16x8 af = *(const bf16x8*)(kl + rk * 64 + slot * 8);
                s = __builtin_amdgcn_mfma_f32_32x32x16_bf16(af, qf[c], s, 0, 0, 0);
            }
            // D: col=lane&31 (=q), row=(reg&3)+8*(reg>>2)+4*hi (=key within block)
#pragma unroll
            for (int g2 = 0; g2 < 4; ++g2) {
                float p0 = __builtin_amdgcn_exp2f(s[4 * g2 + 0]);
                float p1 = __builtin_amdgcn_exp2f(s[4 * g2 + 1]);
                float p2 = __builtin_amdgcn_exp2f(s[4 * g2 + 2]);
                float p3 = __builtin_amdgcn_exp2f(s[4 * g2 + 3]);
                l_part += (p0 + p1) + (p2 + p3);
                uint2 pw;
                pw.x = pk_bf16(p0, p1);
                pw.y = pk_bf16(p2, p3);
                int k0 = kb2 * 32 + 8 * g2 + 4 * hi;
                *(uint2*)(prow + k0) = pw;   // P[q][key], pitch 68: conflict-free b64
            }
        }
        // wave-local P RAW: each wave reads only its own 32 q rows

        // O += P V: A = P (m=q, k=key), B = V (n=d, k=key)
#pragma unroll
        for (int c = 0; c < 4; ++c) {
            u16x4 pa = *(const u16x4*)(prow + 16 * c + 8 * hi);
            u16x4 pb = *(const u16x4*)(prow + 16 * c + 8 * hi + 4);
            bf16x8 pf;
#pragma unroll
            for (int t2 = 0; t2 < 4; ++t2) { pf[t2] = (short)pa[t2]; pf[t2 + 4] = (short)pb[t2]; }
#pragma unroll
            for (int dt = 0; dt < 2; ++dt) {
                int d = dt * 32 + lm32;
                int slot = (2 * c + hi) ^ (d & 7);
                bf16x8 vf = *(const bf16x8*)(vl + d * 64 + slot * 8);
                o_acc[dt] = __builtin_amdgcn_mfma_f32_32x32x16_bf16(pf, vf, o_acc[dt], 0, 0, 0);
            }
        }
    }

    // l: lane covers keys with bit2==hi pattern; partner lane^32 has the rest
    l_part += __shfl_xor(l_part, 32);

    __syncthreads();   // all waves done with kv/p; overlay o_lds
    if (hi == 0) l_lds[qrow] = 1.0f / l_part;
    // o_acc: col = lane&31 -> d = dt*32+lm32; rows q = wr + 8*g2 + 4*hi + r
#pragma unroll
    for (int dt = 0; dt < 2; ++dt) {
        int d = dt * 32 + lm32;
#pragma unroll
        for (int g2 = 0; g2 < 4; ++g2) {
            f32x4 vq;
#pragma unroll
            for (int r = 0; r < 4; ++r) vq[r] = o_acc[dt][4 * g2 + r];
            *(f32x4*)(o_lds + d * 132 + wr + 8 * g2 + 4 * hi) = vq;
        }
    }
    __syncthreads();
    float* ob = out + ((size_t)b * DM + h_ * 64) * L_SEQ + q0;
#pragma unroll
    for (int p = 0; p < 8; ++p) {
        int id = p * 256 + tid;
        int d = id >> 5, rc = id & 31;
        f32x4 vv = *(const f32x4*)(o_lds + d * 132 + rc * 4);
        f32x4 il = *(const f32x4*)(l_lds + rc * 4);
#pragma unroll
        for (int j = 0; j < 4; ++j) vv[j] *= il[j];
        *(f32x4*)(ob + (size_t)d * L_SEQ + rc * 4) = vv;
    }
}

extern "C" void kernel_launch(void* const* d_in, const int* in_sizes, int n_in,
                              void* d_out, int out_size, void* d_ws, size_t ws_size,
                              hipStream_t stream) {
    const float* x1 = (const float*)d_in[0];
    const float* x2 = (const float*)d_in[1];
    const float* Wq = (const float*)d_in[2];
    const float* bq = (const float*)d_in[3];
    const float* Wk = (const float*)d_in[4];
    const float* bk = (const float*)d_in[5];
    const float* Wv = (const float*)d_in[6];
    const float* bv = (const float*)d_in[7];
    float* out = (float*)d_out;

    char* ws = (char*)d_ws;
    u16* x1T = (u16*)(ws);
    u16* x2T = (u16*)(ws + 8388608);
    u16* Wall = (u16*)(ws + 16777216);
    u16* Qb  = (u16*)(ws + 18350080);
    u16* Kb  = (u16*)(ws + 26738688);
    u16* Vtb = (u16*)(ws + 35127296);

    cvt_w<<<768, 256, 0, stream>>>(Wq, Wk, Wv, Wall);
    tr_cvt_x<<<dim3(16, 4, 8), 256, 0, stream>>>(x1, x2, x1T);
    proj_gemm<<<dim3(64, 12), 256, 0, stream>>>(x1T, x2T, Wall, bq, bk, bv, Qb, Kb, Vtb);
    attn<<<512, 256, 0, stream>>>(Qb, Kb, Vtb, out);
}